// Round 2
// baseline (285.660 us; speedup 1.0000x reference)
//
#include <hip/hip_runtime.h>
#include <stdint.h>

#define D_DIM 1024
#define M_DIM 128
#define BR 128
#define BD 64
#define NCHUNK (D_DIM / BD)   // 16

// Bit-exact semantics (verified R7, absmax=0.0):
//   h[r][m]  = sequential __fmaf_rn chain over d = 0..1023 (ascending)
//   FWHT stages on column-bit 0,1,...,6 ascending; out[bit]=a+b / a-b, fp32
//   bit = (h > 0) ? 1.0f : 0.0f
//
// R9: 8x8 per-thread tile (block tile 128x128, grid=256 = 1 block/CU).
//   Halves ds_read_b128 count per FMA vs R8's 4x8 tile: (8+8) reads per
//   256 FMAs -> LDS pipe ~= FMA pipe (was 1.5-2.25x over).
//   - double-buffered LDS (2 x 64 KB = 128 KB), one __syncthreads per
//     chunk; next chunk's global_load_lds in flight across whole compute.
//   - both tiles are [128 rows][16 x 16B chunks]; bank-deswizzle via the
//     GLOBAL source address: logical chunk (r,cj) stored at physical
//     r*16 + (cj ^ ((r>>3)&15)); read side applies the same XOR.
//     Granule spread (cj^tcol)&7 -> 2-way = free.
//   - 1 wave/SIMD: latency hiding is pure ILP (64 indep FMA chains).

typedef const __attribute__((address_space(1))) void* gas_cptr;
typedef __attribute__((address_space(3))) void* lds_vptr;

__device__ __forceinline__ void gload_lds16(const float* g, float* l) {
    __builtin_amdgcn_global_load_lds((gas_cptr)g, (lds_vptr)l, 16, 0, 0);
}

__global__ __launch_bounds__(256, 1)
void rewa_kernel(const float* __restrict__ X, const float* __restrict__ W,
                 float* __restrict__ out) {
    #pragma clang fp contract(off)
    __shared__ float wsh[2][M_DIM * BD];   // 2 x 32 KB, chunk-swizzled
    __shared__ float xs [2][BR * BD];      // 2 x 32 KB, chunk-swizzled

    const int t    = threadIdx.x;
    const int lane = t & 63;
    const int wave = t >> 6;                       // 0..3
    const int tcol = lane & 15;                    // cols 8*tcol .. 8*tcol+7
    const int trow = (wave << 2) + (lane >> 4);    // rows 8*trow .. 8*trow+7
    const size_t row0 = (size_t)blockIdx.x * BR;

    // Per-lane staging sources, pre-applying the inverse read swizzle.
    // Both tiles use the identical (row, chunk) mapping.
    const float* wsrc[8];
    const float* xsrc[8];
    {
        const int p   = lane & 15;
        const int sub = lane >> 4;
        #pragma unroll
        for (int q = 0; q < 8; ++q) {
            const int inst = wave * 8 + q;          // 0..31
            const int r    = inst * 4 + sub;        // 0..127
            const int cj   = p ^ ((r >> 3) & 15);
            wsrc[q] = W + (size_t)r * D_DIM + 4 * cj;
            xsrc[q] = X + (row0 + r) * D_DIM + 4 * cj;
        }
    }

    float acc[8][8];   // [ci][rr]
    #pragma unroll
    for (int ci = 0; ci < 8; ++ci)
        #pragma unroll
        for (int rr = 0; rr < 8; ++rr) acc[ci][rr] = 0.0f;

    // prologue: stage chunk 0 into buffer 0
    #pragma unroll
    for (int q = 0; q < 8; ++q)
        gload_lds16(wsrc[q], &wsh[0][(wave * 8 + q) * 256]);
    #pragma unroll
    for (int q = 0; q < 8; ++q)
        gload_lds16(xsrc[q], &xs[0][(wave * 8 + q) * 256]);

    for (int ch = 0; ch < NCHUNK; ++ch) {
        __syncthreads();           // chunk ch visible; prev chunk's reads done
        const int buf = ch & 1;
        if (ch + 1 < NCHUNK) {     // issue next chunk; lands during compute
            const int d0n = (ch + 1) * BD;
            #pragma unroll
            for (int q = 0; q < 8; ++q)
                gload_lds16(wsrc[q] + d0n, &wsh[buf ^ 1][(wave * 8 + q) * 256]);
            #pragma unroll
            for (int q = 0; q < 8; ++q)
                gload_lds16(xsrc[q] + d0n, &xs [buf ^ 1][(wave * 8 + q) * 256]);
        }

        const float* wb = &wsh[buf][0];
        const float* xb = &xs [buf][0];
        // compute: j ascending (bit-exact chain order)
        #pragma unroll 2
        for (int j4 = 0; j4 < BD; j4 += 4) {
            const int cj = j4 >> 2;
            const int pw = (cj ^ tcol) << 2;   // swizzled float offset in row
            const int px = (cj ^ trow) << 2;
            float4 wf[8], xf[8];
            #pragma unroll
            for (int ci = 0; ci < 8; ++ci)
                wf[ci] = *(const float4*)&wb[(8 * tcol + ci) * BD + pw];
            #pragma unroll
            for (int rr = 0; rr < 8; ++rr)
                xf[rr] = *(const float4*)&xb[(8 * trow + rr) * BD + px];
            #pragma unroll
            for (int e = 0; e < 4; ++e) {
                #pragma unroll
                for (int rr = 0; rr < 8; ++rr) {
                    const float xv = ((const float*)&xf[rr])[e];
                    #pragma unroll
                    for (int ci = 0; ci < 8; ++ci)
                        acc[ci][rr] = __fmaf_rn(xv, ((const float*)&wf[ci])[e],
                                                acc[ci][rr]);
                }
            }
        }
    }

    // ---- FWHT, fp32, ascending column bits. col = 8*tcol + ci ----
    // bits 0,1,2 live in ci (register butterflies, FIRST)
    #pragma unroll
    for (int rr = 0; rr < 8; ++rr) {
        const float a0 = acc[0][rr], a1 = acc[1][rr];
        const float a2 = acc[2][rr], a3 = acc[3][rr];
        const float a4 = acc[4][rr], a5 = acc[5][rr];
        const float a6 = acc[6][rr], a7 = acc[7][rr];
        // bit 0
        const float b0 = __fadd_rn(a0, a1), b1 = __fsub_rn(a0, a1);
        const float b2 = __fadd_rn(a2, a3), b3 = __fsub_rn(a2, a3);
        const float b4 = __fadd_rn(a4, a5), b5 = __fsub_rn(a4, a5);
        const float b6 = __fadd_rn(a6, a7), b7 = __fsub_rn(a6, a7);
        // bit 1
        const float c0 = __fadd_rn(b0, b2), c1 = __fadd_rn(b1, b3);
        const float c2 = __fsub_rn(b0, b2), c3 = __fsub_rn(b1, b3);
        const float c4 = __fadd_rn(b4, b6), c5 = __fadd_rn(b5, b7);
        const float c6 = __fsub_rn(b4, b6), c7 = __fsub_rn(b5, b7);
        // bit 2
        acc[0][rr] = __fadd_rn(c0, c4);
        acc[1][rr] = __fadd_rn(c1, c5);
        acc[2][rr] = __fadd_rn(c2, c6);
        acc[3][rr] = __fadd_rn(c3, c7);
        acc[4][rr] = __fsub_rn(c0, c4);
        acc[5][rr] = __fsub_rn(c1, c5);
        acc[6][rr] = __fsub_rn(c2, c6);
        acc[7][rr] = __fsub_rn(c3, c7);
    }
    // bits 3..6 live in tcol = lane bits 0..3 (lane>>4 same on both ends)
    #pragma unroll
    for (int h = 1; h <= 8; h <<= 1) {
        const bool up = (tcol & h) != 0;
        #pragma unroll
        for (int ci = 0; ci < 8; ++ci)
            #pragma unroll
            for (int rr = 0; rr < 8; ++rr) {
                const float mine  = acc[ci][rr];
                const float other = __shfl_xor(mine, h, 64);
                acc[ci][rr] = up ? __fsub_rn(other, mine)
                                 : __fadd_rn(mine, other);
            }
    }

    // sign + float4 stores (two per row, cols 8*tcol..+7)
    #pragma unroll
    for (int rr = 0; rr < 8; ++rr) {
        const size_t row = row0 + 8 * trow + rr;
        float4 v0, v1;
        v0.x = (acc[0][rr] > 0.0f) ? 1.0f : 0.0f;
        v0.y = (acc[1][rr] > 0.0f) ? 1.0f : 0.0f;
        v0.z = (acc[2][rr] > 0.0f) ? 1.0f : 0.0f;
        v0.w = (acc[3][rr] > 0.0f) ? 1.0f : 0.0f;
        v1.x = (acc[4][rr] > 0.0f) ? 1.0f : 0.0f;
        v1.y = (acc[5][rr] > 0.0f) ? 1.0f : 0.0f;
        v1.z = (acc[6][rr] > 0.0f) ? 1.0f : 0.0f;
        v1.w = (acc[7][rr] > 0.0f) ? 1.0f : 0.0f;
        *(float4*)(out + row * M_DIM + 8 * tcol)     = v0;
        *(float4*)(out + row * M_DIM + 8 * tcol + 4) = v1;
    }
}

extern "C" void kernel_launch(void* const* d_in, const int* in_sizes, int n_in,
                              void* d_out, int out_size, void* d_ws, size_t ws_size,
                              hipStream_t stream) {
    const float* x = (const float*)d_in[0];
    const float* W = (const float*)d_in[1];
    float* out = (float*)d_out;
    const int nrows = out_size / M_DIM;   // 32768

    hipLaunchKernelGGL(rewa_kernel, dim3(nrows / BR), dim3(256), 0, stream,
                       x, W, out);
}